// Round 6
// baseline (77.459 us; speedup 1.0000x reference)
//
#include <hip/hip_runtime.h>
#include <math.h>

// Problem constants
#define NB 2
#define HIMG 96
#define HO 65
#define NCROPS (NB*HO*HO)   // 8450
#define NT16 529            // ceil(8450/16) 16-crop tiles

// pool1: [cls3=(img,o1,o2)][16ch][46][46]
#define P1_PLANE (46*46)          // 2116
#define P1_SIZE (8*16*P1_PLANE)   // 270848
// conv2: [cls3][32ch][44][44]
#define C2_PLANE (44*44)          // 1936
#define C2_SIZE (8*32*C2_PLANE)   // 495616
// pool2: [cls5=(img,o1,o2,p1,p2)][32ch][22][22]
#define P2_PLANE (22*22)          // 484
#define P2_SIZE (32*32*P2_PLANE)  // 495616
// A_blk: [tile 529][ks 36][crop 16][k 32] bf16
#define NIM2 (NT16*36*16)         // 304704 threads, 32 k each

typedef __attribute__((ext_vector_type(8))) short bf16x8;
typedef __attribute__((ext_vector_type(4))) float f32x4;

__device__ __forceinline__ unsigned int f2bf(float x) {
    unsigned int u = __builtin_bit_cast(unsigned int, x);
    return (u + 0x7fffu + ((u >> 16) & 1u)) >> 16;
}

// Merged front kernel:
//   blocks [0,529)   : conv1(5x5,1->16)+ReLU+2x2 maxpool at parity -> pool1
//   blocks [529,601) : cast fc1_w -> bf16 wB[n][k]
//   blocks [601,673) : zero heatmap
__global__ void k_front(const float* __restrict__ x, const float* __restrict__ w1,
                        const float* __restrict__ b1, float* __restrict__ pool1,
                        const float* __restrict__ fc1_w, unsigned short* __restrict__ wB,
                        float* __restrict__ out) {
    int b = blockIdx.x, tid = threadIdx.x;
    if (b >= 529) {
        if (b < 601) {
            int t = (b - 529) * 256 + tid;            // < 18432, 8 elements each
            const float4* src = (const float4*)fc1_w + t * 2;
            float4 a = src[0], c = src[1];
            uint4 v;
            v.x = f2bf(a.x) | (f2bf(a.y) << 16);
            v.y = f2bf(a.z) | (f2bf(a.w) << 16);
            v.z = f2bf(c.x) | (f2bf(c.y) << 16);
            v.w = f2bf(c.z) | (f2bf(c.w) << 16);
            ((uint4*)wB)[t] = v;
        } else {
            out[(b - 601) * 256 + tid] = 0.f;
        }
        return;
    }
    int idx = b * 256 + tid;                          // < 135424
    int pg = idx % 23;
    int t  = idx / 23;
    int py = t % 46;  t /= 46;
    int ch = t % 16;  t /= 16;                        // t = cls3
    int o2 = t & 1, o1 = (t >> 1) & 1, img = t >> 2;
    const float* xim = x + img * (HIMG * HIMG);

    int rbase = 2 * py + o1;
    int cbase = 4 * pg + o2;
    float a[6][8];
    #pragma unroll
    for (int i = 0; i < 6; ++i) {
        int r = rbase + i; if (r > 95) r = 95;
        const float* rp = xim + r * 96;
        #pragma unroll
        for (int j = 0; j < 8; ++j) {
            int c = cbase + j; if (c > 95) c = 95;
            a[i][j] = rp[c];
        }
    }
    const float* wc = w1 + ch * 25;
    float w[25];
    #pragma unroll
    for (int u = 0; u < 25; ++u) w[u] = wc[u];
    float bias = b1[ch];

    float out0 = 0.f, out1 = 0.f;   // relu'd values >= 0
    #pragma unroll
    for (int dy = 0; dy < 2; ++dy)
        #pragma unroll
        for (int dx = 0; dx < 2; ++dx) {
            float s0 = bias, s1 = bias;
            #pragma unroll
            for (int ky = 0; ky < 5; ++ky)
                #pragma unroll
                for (int kx = 0; kx < 5; ++kx) {
                    float wv = w[ky * 5 + kx];
                    s0 += a[dy + ky][dx + kx] * wv;
                    s1 += a[dy + ky][2 + dx + kx] * wv;
                }
            out0 = fmaxf(out0, s0);
            out1 = fmaxf(out1, s1);
        }
    int base = ((t * 16 + ch) * 46 + py) * 46 + 2 * pg;
    float2 v; v.x = out0; v.y = out1;
    *(float2*)&pool1[base] = v;
}

// conv2(3x3,16->32)+ReLU; 4 outputs along x per thread, float4 store.
__global__ void k_conv2(const float* __restrict__ pool1, const float* __restrict__ w2,
                        const float* __restrict__ b2, float* __restrict__ conv2) {
    int idx = blockIdx.x * 256 + threadIdx.x;     // < 123904
    int og = idx % 11;
    int t  = idx / 11;
    int oy = t % 44;  t /= 44;
    int oc = t % 32;  t /= 32;                    // t = cls3
    int ox0 = og * 4;
    const float* p1 = pool1 + t * 16 * P1_PLANE + oy * 46 + ox0;
    const float* ww = w2 + oc * 144;
    float b = b2[oc];
    float s0 = b, s1 = b, s2 = b, s3 = b;
    for (int ic = 0; ic < 16; ++ic) {
        const float* pp = p1 + ic * P1_PLANE;
        const float* wk = ww + ic * 9;
        #pragma unroll
        for (int ky = 0; ky < 3; ++ky) {
            const float* r = pp + ky * 46;
            float w0 = wk[ky * 3], w1v = wk[ky * 3 + 1], w2v = wk[ky * 3 + 2];
            float a0 = r[0], a1 = r[1], a2 = r[2], a3 = r[3], a4 = r[4], a5 = r[5];
            s0 += a0 * w0 + a1 * w1v + a2 * w2v;
            s1 += a1 * w0 + a2 * w1v + a3 * w2v;
            s2 += a2 * w0 + a3 * w1v + a4 * w2v;
            s3 += a3 * w0 + a4 * w1v + a5 * w2v;
        }
    }
    float4 v;
    v.x = fmaxf(s0, 0.f); v.y = fmaxf(s1, 0.f);
    v.z = fmaxf(s2, 0.f); v.w = fmaxf(s3, 0.f);
    *(float4*)&conv2[(t * 32 + oc) * C2_PLANE + oy * 44 + ox0] = v;
}

// Second 2x2 maxpool at sub-parity (p1,p2) -> 32 classes.
__global__ void k_pool2(const float* __restrict__ conv2, float* __restrict__ pool2) {
    int idx = blockIdx.x * 256 + threadIdx.x;     // < 495616
    int ex = idx % 22;
    int t  = idx / 22;
    int ey = t % 22;  t /= 22;
    int ch = t % 32;  t /= 32;                    // t = cls5
    int p2 = t & 1, p1 = (t >> 1) & 1;
    int cls3 = t >> 2;
    const float* c2 = conv2 + (cls3 * 32 + ch) * C2_PLANE;
    int r0 = 2 * ey + p1, r1 = r0 + 1; if (r0 > 43) r0 = 43; if (r1 > 43) r1 = 43;
    int c0 = 2 * ex + p2, c1 = c0 + 1; if (c0 > 43) c0 = 43; if (c1 > 43) c1 = 43;
    float v = fmaxf(fmaxf(c2[r0 * 44 + c0], c2[r0 * 44 + c1]),
                    fmaxf(c2[r1 * 44 + c0], c2[r1 * 44 + c1]));
    pool2[idx] = v;
}

// im2col: materialize A_blk[tile][ks][crop 16][k 32] bf16.
// Thread g = tile*576 + ks*16 + crop gathers 32 k's via LDS offset table,
// writes 64 B contiguous (consecutive threads -> consecutive 64 B).
__global__ void k_im2col(const float* __restrict__ pool2, unsigned short* __restrict__ A_blk) {
    __shared__ unsigned int shOff[1152];
    int tid = threadIdx.x;
    for (int k = tid; k < 1152; k += 256) {
        int ch = k / 36, rr = k - ch * 36, mm = rr / 6, nn = rr - mm * 6;
        shOff[k] = ch * P2_PLANE + mm * 22 + nn;
    }
    __syncthreads();

    int g = blockIdx.x * 256 + tid;
    if (g >= NIM2) return;
    int crop = g & 15;
    int t = g >> 4;
    int ks = t % 36;
    int tile = t / 36;

    int cid = tile * 16 + crop;
    int cidc = cid < NCROPS ? cid : NCROPS - 1;
    int img = cidc / 4225;
    int rem = cidc - img * 4225;
    int i = rem / 65, j = rem - i * 65;
    int o1 = i & 1, p1 = (i >> 1) & 1, c = i >> 2;
    int o2 = j & 1, p2 = (j >> 1) & 1, d = j >> 2;
    int cls5 = (((img * 2 + o1) * 2 + o2) * 2 + p1) * 2 + p2;
    const float* pbase = pool2 + cls5 * 32 * P2_PLANE + c * 22 + d;

    int k0 = ks * 32;
    unsigned int v[16];
    #pragma unroll
    for (int e = 0; e < 16; ++e) {
        unsigned int off0 = shOff[k0 + 2 * e];
        unsigned int off1 = shOff[k0 + 2 * e + 1];
        v[e] = f2bf(pbase[off0]) | (f2bf(pbase[off1]) << 16);
    }
    uint4* dst = (uint4*)(A_blk + (unsigned)g * 32);
    #pragma unroll
    for (int q = 0; q < 4; ++q) {
        uint4 w; w.x = v[4*q]; w.y = v[4*q+1]; w.z = v[4*q+2]; w.w = v[4*q+3];
        dst[q] = w;
    }
}

// FC GEMM, zero-LDS-staging: A fragments are coalesced global loads from A_blk,
// B fragments stream from L2-hot wB. 8 waves = 4 N-slices x 2 K-halves;
// K-half partials summed through LDS H; fused bias/ReLU/FC2/sigmoid/scatter.
__global__ __launch_bounds__(512, 4) void k_fc(const unsigned short* __restrict__ A_blk,
                                               const unsigned short* __restrict__ wB,
                                               const float* __restrict__ fc1_b,
                                               const float* __restrict__ fc2_w,
                                               const float* __restrict__ fc2_b,
                                               float* __restrict__ out) {
    __shared__ __align__(16) float shH[16][132];

    int tid  = threadIdx.x;
    int tile = blockIdx.x;           // < 529
    int lane = tid & 63, wid = tid >> 6;
    int nsl = wid & 3, kh = wid >> 2;
    int lm = lane & 15, lg = lane >> 4;

    // A: [tile][ks][crop 16][k 32]; this wave's half starts at ks = kh*18
    const unsigned short* ap = A_blk + ((unsigned)(tile * 36 + kh * 18) * 16 + lm) * 32 + lg * 8;
    // B: wB[n][k], n = nsl*32 + {lm, 16+lm}, k offset kh*576
    const unsigned short* bp0 = wB + (nsl * 32 + lm) * 1152 + kh * 576 + lg * 8;
    const unsigned short* bp1 = bp0 + 16 * 1152;

    f32x4 acc0 = {0.f, 0.f, 0.f, 0.f};
    f32x4 acc1 = {0.f, 0.f, 0.f, 0.f};

    #pragma unroll 6
    for (int ki = 0; ki < 18; ++ki) {
        bf16x8 av = *(const bf16x8*)(ap + ki * 512);
        bf16x8 b0 = *(const bf16x8*)(bp0 + ki * 32);
        bf16x8 b1 = *(const bf16x8*)(bp1 + ki * 32);
        acc0 = __builtin_amdgcn_mfma_f32_16x16x32_bf16(av, b0, acc0, 0, 0, 0);
        acc1 = __builtin_amdgcn_mfma_f32_16x16x32_bf16(av, b1, acc1, 0, 0, 0);
    }

    // Reduce the two K-halves via LDS. D layout (empirical, R3-verified):
    // first-operand row = lg*4+r, second-operand row = lm.
    if (kh == 0) {
        #pragma unroll
        for (int r = 0; r < 4; ++r) {
            shH[lg * 4 + r][nsl * 32 + lm]      = acc0[r];
            shH[lg * 4 + r][nsl * 32 + 16 + lm] = acc1[r];
        }
    }
    __syncthreads();
    if (kh == 1) {
        #pragma unroll
        for (int r = 0; r < 4; ++r) {
            shH[lg * 4 + r][nsl * 32 + lm]      += acc0[r];
            shH[lg * 4 + r][nsl * 32 + 16 + lm] += acc1[r];
        }
    }
    __syncthreads();

    // FC2: 512 thr = 16 crops x 32 parts, 4 elems each; reduce within 32 lanes.
    int crop_l = tid >> 5, part = tid & 31;
    float4 h  = *(const float4*)&shH[crop_l][part * 4];
    float4 fb = *(const float4*)&fc1_b[part * 4];
    float4 w  = *(const float4*)&fc2_w[part * 4];
    float s = fmaxf(h.x + fb.x, 0.f) * w.x
            + fmaxf(h.y + fb.y, 0.f) * w.y
            + fmaxf(h.z + fb.z, 0.f) * w.z
            + fmaxf(h.w + fb.w, 0.f) * w.w;
    s += __shfl_down(s, 16, 32);
    s += __shfl_down(s, 8, 32);
    s += __shfl_down(s, 4, 32);
    s += __shfl_down(s, 2, 32);
    s += __shfl_down(s, 1, 32);
    if (part == 0) {
        int cid = tile * 16 + crop_l;
        if (cid < NCROPS) {
            int img = cid / 4225;
            int rem = cid - img * 4225;
            int i = rem / 65, j = rem - i * 65;
            float q = 1.f / (1.f + expf(-(s + fc2_b[0])));
            out[img * (HIMG * HIMG) + (16 + i) * HIMG + (16 + j)] = q;
        }
    }
}

extern "C" void kernel_launch(void* const* d_in, const int* in_sizes, int n_in,
                              void* d_out, int out_size, void* d_ws, size_t ws_size,
                              hipStream_t stream) {
    const float* x     = (const float*)d_in[0];
    const float* w1    = (const float*)d_in[1];
    const float* b1    = (const float*)d_in[2];
    const float* w2    = (const float*)d_in[3];
    const float* b2    = (const float*)d_in[4];
    const float* fc1_w = (const float*)d_in[5];
    const float* fc1_b = (const float*)d_in[6];
    const float* fc2_w = (const float*)d_in[7];
    const float* fc2_b = (const float*)d_in[8];
    float* out = (float*)d_out;

    float* ws    = (float*)d_ws;
    float* pool1 = ws;                         // 270848 f32
    float* conv2 = pool1 + P1_SIZE;            // 495616 f32
    float* pool2 = conv2 + C2_SIZE;            // 495616 f32
    unsigned short* wB    = (unsigned short*)(pool2 + P2_SIZE);  // 147456 bf16
    unsigned short* A_blk = wB + 128 * 1152;   // 9,750,528 bf16 = 19.5 MB

    k_front<<<673, 256, 0, stream>>>(x, w1, b1, pool1, fc1_w, wB, out);
    k_conv2<<<484, 256, 0, stream>>>(pool1, w2, b2, conv2);
    k_pool2<<<C2_SIZE / 256, 256, 0, stream>>>(conv2, pool2);
    k_im2col<<<(NIM2 + 255) / 256, 256, 0, stream>>>(pool2, A_blk);
    k_fc<<<NT16, 512, 0, stream>>>(A_blk, wB, fc1_b, fc2_w, fc2_b, out);
}

// Round 7
// 56.557 us; speedup vs baseline: 1.3696x; 1.3696x over previous
//
#include <hip/hip_runtime.h>
#include <math.h>

// Problem constants
#define NB 2
#define HIMG 96
#define HO 65
#define NCROPS (NB*HO*HO)   // 8450

// pool1: [cls3=(img,o1,o2)][16ch][46][46]
#define P1_PLANE (46*46)          // 2116
#define P1_SIZE (8*16*P1_PLANE)   // 270848
// conv2: [cls3][32ch][44][44]
#define C2_PLANE (44*44)          // 1936
#define C2_SIZE (8*32*C2_PLANE)   // 495616
// pool2: [cls5=(img,o1,o2,p1,p2)][32ch][22][22] f32
#define P2_PLANE (22*22)          // 484
#define P2_SIZE (32*32*P2_PLANE)  // 495616
// wBt: fragment-blocked padded weights [nf 8][ki 48][lane 64][8] bf16
#define WBT_SIZE (8*48*64*8)      // 196608

typedef __attribute__((ext_vector_type(8))) short bf16x8;
typedef __attribute__((ext_vector_type(4))) float f32x4;
typedef __attribute__((ext_vector_type(4), aligned(4))) float f32x4u;  // 4B-aligned vec load
typedef __attribute__((ext_vector_type(4))) unsigned int u32x4;

__device__ __forceinline__ unsigned int f2bf(float x) {
    unsigned int u = __builtin_bit_cast(unsigned int, x);
    return (u + 0x7fffu + ((u >> 16) & 1u)) >> 16;
}
__device__ __forceinline__ unsigned int cvtpk(float lo, float hi) {
    unsigned int r;
    asm("v_cvt_pk_bf16_f32 %0, %1, %2" : "=v"(r) : "v"(lo), "v"(hi));
    return r;
}

// Merged front kernel:
//   blocks [0,529)   : conv1(5x5,1->16)+ReLU+2x2 maxpool at parity -> pool1
//   blocks [529,625) : build wBt (fragment-blocked, nn'-padded bf16 fc1 weights)
//   blocks [625,697) : zero heatmap
__global__ void k_front(const float* __restrict__ x, const float* __restrict__ w1,
                        const float* __restrict__ b1, float* __restrict__ pool1,
                        const float* __restrict__ fc1_w, unsigned short* __restrict__ wBt,
                        float* __restrict__ out) {
    int b = blockIdx.x, tid = threadIdx.x;
    if (b >= 529) {
        if (b < 625) {
            int g = (b - 529) * 256 + tid;        // < 24576, one 16B chunk each
            int l = g & 63;
            int t2 = g >> 6;                      // < 384
            int ki = t2 % 48, nf = t2 / 48;
            int n  = nf * 16 + (l & 15);
            int lg = l >> 4;
            int ch = (ki & 7) * 4 + lg;           // matches k_fc: ch=((kk*4)&31)+lg
            int mm = (ki / 24) * 3 + ((ki >> 3) % 3);  // matches k_fc: mm=kh*3+(kk>>3)
            const float* src = fc1_w + n * 1152 + ch * 36 + mm * 6;
            uint4 v;
            v.x = f2bf(src[0]) | (f2bf(src[1]) << 16);
            v.y = f2bf(src[2]) | (f2bf(src[3]) << 16);
            v.z = f2bf(src[4]) | (f2bf(src[5]) << 16);
            v.w = 0;                              // nn' = 6,7 zero-padded
            ((uint4*)wBt)[g] = v;
        } else {
            out[(b - 625) * 256 + tid] = 0.f;
        }
        return;
    }
    int idx = b * 256 + tid;                          // < 135424
    int pg = idx % 23;
    int t  = idx / 23;
    int py = t % 46;  t /= 46;
    int ch = t % 16;  t /= 16;                        // t = cls3
    int o2 = t & 1, o1 = (t >> 1) & 1, img = t >> 2;
    const float* xim = x + img * (HIMG * HIMG);

    int rbase = 2 * py + o1;
    int cbase = 4 * pg + o2;
    float a[6][8];
    #pragma unroll
    for (int i = 0; i < 6; ++i) {
        int r = rbase + i; if (r > 95) r = 95;
        const float* rp = xim + r * 96;
        #pragma unroll
        for (int j = 0; j < 8; ++j) {
            int c = cbase + j; if (c > 95) c = 95;
            a[i][j] = rp[c];
        }
    }
    const float* wc = w1 + ch * 25;
    float w[25];
    #pragma unroll
    for (int u = 0; u < 25; ++u) w[u] = wc[u];
    float bias = b1[ch];

    float out0 = 0.f, out1 = 0.f;   // relu'd values >= 0
    #pragma unroll
    for (int dy = 0; dy < 2; ++dy)
        #pragma unroll
        for (int dx = 0; dx < 2; ++dx) {
            float s0 = bias, s1 = bias;
            #pragma unroll
            for (int ky = 0; ky < 5; ++ky)
                #pragma unroll
                for (int kx = 0; kx < 5; ++kx) {
                    float wv = w[ky * 5 + kx];
                    s0 += a[dy + ky][dx + kx] * wv;
                    s1 += a[dy + ky][2 + dx + kx] * wv;
                }
            out0 = fmaxf(out0, s0);
            out1 = fmaxf(out1, s1);
        }
    int base = ((t * 16 + ch) * 46 + py) * 46 + 2 * pg;
    float2 v; v.x = out0; v.y = out1;
    *(float2*)&pool1[base] = v;
}

// conv2(3x3,16->32)+ReLU; 4 outputs along x per thread, float4 store.
__global__ void k_conv2(const float* __restrict__ pool1, const float* __restrict__ w2,
                        const float* __restrict__ b2, float* __restrict__ conv2) {
    int idx = blockIdx.x * 256 + threadIdx.x;     // < 123904
    int og = idx % 11;
    int t  = idx / 11;
    int oy = t % 44;  t /= 44;
    int oc = t % 32;  t /= 32;                    // t = cls3
    int ox0 = og * 4;
    const float* p1 = pool1 + t * 16 * P1_PLANE + oy * 46 + ox0;
    const float* ww = w2 + oc * 144;
    float b = b2[oc];
    float s0 = b, s1 = b, s2 = b, s3 = b;
    for (int ic = 0; ic < 16; ++ic) {
        const float* pp = p1 + ic * P1_PLANE;
        const float* wk = ww + ic * 9;
        #pragma unroll
        for (int ky = 0; ky < 3; ++ky) {
            const float* r = pp + ky * 46;
            float w0 = wk[ky * 3], w1v = wk[ky * 3 + 1], w2v = wk[ky * 3 + 2];
            float a0 = r[0], a1 = r[1], a2 = r[2], a3 = r[3], a4 = r[4], a5 = r[5];
            s0 += a0 * w0 + a1 * w1v + a2 * w2v;
            s1 += a1 * w0 + a2 * w1v + a3 * w2v;
            s2 += a2 * w0 + a3 * w1v + a4 * w2v;
            s3 += a3 * w0 + a4 * w1v + a5 * w2v;
        }
    }
    float4 v;
    v.x = fmaxf(s0, 0.f); v.y = fmaxf(s1, 0.f);
    v.z = fmaxf(s2, 0.f); v.w = fmaxf(s3, 0.f);
    *(float4*)&conv2[(t * 32 + oc) * C2_PLANE + oy * 44 + ox0] = v;
}

// Second 2x2 maxpool at sub-parity (p1,p2) -> 32 classes (f32).
__global__ void k_pool2(const float* __restrict__ conv2, float* __restrict__ pool2) {
    int idx = blockIdx.x * 256 + threadIdx.x;     // < 495616
    int ex = idx % 22;
    int t  = idx / 22;
    int ey = t % 22;  t /= 22;
    int ch = t % 32;  t /= 32;                    // t = cls5
    int p2 = t & 1, p1 = (t >> 1) & 1;
    int cls3 = t >> 2;
    const float* c2 = conv2 + (cls3 * 32 + ch) * C2_PLANE;
    int r0 = 2 * ey + p1, r1 = r0 + 1; if (r0 > 43) r0 = 43; if (r1 > 43) r1 = 43;
    int c0 = 2 * ex + p2, c1 = c0 + 1; if (c0 > 43) c0 = 43; if (c1 > 43) c1 = 43;
    float v = fmaxf(fmaxf(c2[r0 * 44 + c0], c2[r0 * 44 + c1]),
                    fmaxf(c2[r1 * 44 + c0], c2[r1 * 44 + c1]));
    pool2[idx] = v;
}

// FC GEMM with contiguous-M ordering: m = cls5*289 + c*17 + d  (d fastest).
// A-fragment loads are near-contiguous plane-row reads (no lane scatter);
// B streams from fragment-blocked wBt (1KB contiguous per instruction).
// K' = 1536 (nn' padded 6->8, zero weights). 8 waves = 4 N-slices x 2 K-halves;
// halves reduced via LDS; fused bias/ReLU/FC2/sigmoid/scatter.
__global__ __launch_bounds__(512, 4) void k_fc(const float* __restrict__ pool2,
                                               const unsigned short* __restrict__ wBt,
                                               const float* __restrict__ fc1_b,
                                               const float* __restrict__ fc2_w,
                                               const float* __restrict__ fc2_b,
                                               float* __restrict__ out) {
    __shared__ __align__(16) float shH[32][132];

    int tid  = threadIdx.x;
    int lane = tid & 63, wid = tid >> 6;
    int nsl = wid & 3, kh = wid >> 2;       // N-slice, K-half
    int lm = lane & 15, lg = lane >> 4;
    int m0 = blockIdx.x * 32;

    // Per-lane A base pointers (two M-fragments). ch = ((kk*4)&31)+lg, mm = kh*3+(kk>>3)
    // fold lg and kh in once: + lg*484 + kh*3*22.
    const float* aF0;
    const float* aF1;
    {
        int m = m0 + lm;
        int cls5 = m / 289, r = m - cls5 * 289;
        int c = r / 17, d = r - c * 17;
        aF0 = pool2 + cls5 * (32 * P2_PLANE) + c * 22 + d + lg * P2_PLANE + kh * 66;
        m += 16;
        cls5 = m / 289; r = m - cls5 * 289;
        c = r / 17; d = r - c * 17;
        aF1 = pool2 + cls5 * (32 * P2_PLANE) + c * 22 + d + lg * P2_PLANE + kh * 66;
    }
    const unsigned short* bp0 = wBt + (((nsl * 2) * 48 + kh * 24) * 64 + lane) * 8;
    const unsigned short* bp1 = bp0 + 48 * 64 * 8;

    f32x4 acc00 = {0.f,0.f,0.f,0.f}, acc01 = {0.f,0.f,0.f,0.f};
    f32x4 acc10 = {0.f,0.f,0.f,0.f}, acc11 = {0.f,0.f,0.f,0.f};

    #pragma unroll 4
    for (int kk = 0; kk < 24; ++kk) {
        int S = (kk & 7) * (4 * P2_PLANE) + (kk >> 3) * 22;   // (ch-lg)*484 + (mm-kh*3)*22
        f32x4u lo0 = *(const f32x4u*)(aF0 + S);
        f32x4u hi0 = *(const f32x4u*)(aF0 + S + 4);
        f32x4u lo1 = *(const f32x4u*)(aF1 + S);
        f32x4u hi1 = *(const f32x4u*)(aF1 + S + 4);
        bf16x8 b0 = *(const bf16x8*)(bp0 + kk * 512);
        bf16x8 b1 = *(const bf16x8*)(bp1 + kk * 512);
        u32x4 u0 = { cvtpk(lo0.x, lo0.y), cvtpk(lo0.z, lo0.w),
                     cvtpk(hi0.x, hi0.y), cvtpk(hi0.z, hi0.w) };
        u32x4 u1 = { cvtpk(lo1.x, lo1.y), cvtpk(lo1.z, lo1.w),
                     cvtpk(hi1.x, hi1.y), cvtpk(hi1.z, hi1.w) };
        bf16x8 a0 = __builtin_bit_cast(bf16x8, u0);
        bf16x8 a1 = __builtin_bit_cast(bf16x8, u1);
        acc00 = __builtin_amdgcn_mfma_f32_16x16x32_bf16(a0, b0, acc00, 0, 0, 0);
        acc01 = __builtin_amdgcn_mfma_f32_16x16x32_bf16(a0, b1, acc01, 0, 0, 0);
        acc10 = __builtin_amdgcn_mfma_f32_16x16x32_bf16(a1, b0, acc10, 0, 0, 0);
        acc11 = __builtin_amdgcn_mfma_f32_16x16x32_bf16(a1, b1, acc11, 0, 0, 0);
    }

    // Reduce the two K-halves via shH. D layout: row = lg*4+r (A-side), col = lm (B-side).
    int col = nsl * 32 + lm;
    if (kh == 0) {
        #pragma unroll
        for (int r = 0; r < 4; ++r) {
            shH[lg * 4 + r][col]           = acc00[r];
            shH[lg * 4 + r][col + 16]      = acc01[r];
            shH[16 + lg * 4 + r][col]      = acc10[r];
            shH[16 + lg * 4 + r][col + 16] = acc11[r];
        }
    }
    __syncthreads();
    if (kh == 1) {
        #pragma unroll
        for (int r = 0; r < 4; ++r) {
            shH[lg * 4 + r][col]           += acc00[r];
            shH[lg * 4 + r][col + 16]      += acc01[r];
            shH[16 + lg * 4 + r][col]      += acc10[r];
            shH[16 + lg * 4 + r][col + 16] += acc11[r];
        }
    }
    __syncthreads();

    // FC2: 512 thr = 32 rows x 16 parts, 8 elems each; reduce within 16 lanes.
    int row = tid >> 4, part = tid & 15;
    const float* hh = shH[row];
    float s = 0.f;
    #pragma unroll
    for (int u = 0; u < 8; ++u)
        s += fmaxf(hh[part * 8 + u] + fc1_b[part * 8 + u], 0.f) * fc2_w[part * 8 + u];
    s += __shfl_down(s, 8, 16);
    s += __shfl_down(s, 4, 16);
    s += __shfl_down(s, 2, 16);
    s += __shfl_down(s, 1, 16);
    if (part == 0) {
        int m = m0 + row;                   // < 9248 always
        int cls5 = m / 289, r2 = m - cls5 * 289;
        int c = r2 / 17, d = r2 - c * 17;
        int img = cls5 >> 4, o1 = (cls5 >> 3) & 1, o2 = (cls5 >> 2) & 1;
        int p1 = (cls5 >> 1) & 1, p2 = cls5 & 1;
        int i = 4 * c + 2 * p1 + o1;
        int j = 4 * d + 2 * p2 + o2;
        if (i <= 64 && j <= 64) {
            float q = 1.f / (1.f + expf(-(s + fc2_b[0])));
            out[img * (HIMG * HIMG) + (16 + i) * HIMG + (16 + j)] = q;
        }
    }
}

extern "C" void kernel_launch(void* const* d_in, const int* in_sizes, int n_in,
                              void* d_out, int out_size, void* d_ws, size_t ws_size,
                              hipStream_t stream) {
    const float* x     = (const float*)d_in[0];
    const float* w1    = (const float*)d_in[1];
    const float* b1    = (const float*)d_in[2];
    const float* w2    = (const float*)d_in[3];
    const float* b2    = (const float*)d_in[4];
    const float* fc1_w = (const float*)d_in[5];
    const float* fc1_b = (const float*)d_in[6];
    const float* fc2_w = (const float*)d_in[7];
    const float* fc2_b = (const float*)d_in[8];
    float* out = (float*)d_out;

    float* ws    = (float*)d_ws;
    float* pool1 = ws;                         // 270848 f32
    float* conv2 = pool1 + P1_SIZE;            // 495616 f32
    float* pool2 = conv2 + C2_SIZE;            // 495616 f32
    unsigned short* wBt = (unsigned short*)(pool2 + P2_SIZE);  // 196608 bf16

    k_front<<<697, 256, 0, stream>>>(x, w1, b1, pool1, fc1_w, wBt, out);
    k_conv2<<<484, 256, 0, stream>>>(pool1, w2, b2, conv2);
    k_pool2<<<C2_SIZE / 256, 256, 0, stream>>>(conv2, pool2);
    k_fc<<<289, 512, 0, stream>>>(pool2, wBt, fc1_b, fc2_w, fc2_b, out);
}